// Round 8
// baseline (109.075 us; speedup 1.0000x reference)
//
#include <hip/hip_runtime.h>
#include <math.h>

#define NB 32
#define NL 2048
#define NH 8
#define NE 64
#define NM 64
#define MRI 128          // 2*NM (re stacked over im)

typedef __attribute__((ext_vector_type(8))) __bf16 bf16x8;
typedef __attribute__((ext_vector_type(2))) __bf16 bf16x2;
typedef __attribute__((ext_vector_type(8))) unsigned short us8;
typedef __attribute__((ext_vector_type(4))) float f32x4;
typedef __attribute__((ext_vector_type(16))) float f32x16;

__device__ __forceinline__ unsigned short f2bf(float x) {
  unsigned int u = __builtin_bit_cast(unsigned int, x);
  u = (u + 0x7fffu + ((u >> 16) & 1u)) >> 16;
  return (unsigned short)u;
}
__device__ __forceinline__ float bf2f(unsigned short u) {
  return __builtin_bit_cast(float, (unsigned int)u << 16);
}
__device__ __forceinline__ unsigned int pk2(float lo, float hi) {
  bf16x2 v;
  v[0] = (__bf16)lo;
  v[1] = (__bf16)hi;
  return __builtin_bit_cast(unsigned int, v);
}
// barrier that does NOT drain vmcnt: LDS-writes visible, global loads stay in flight
__device__ __forceinline__ void bar_lgkm() {
  asm volatile("s_waitcnt lgkmcnt(0)" ::: "memory");
  __builtin_amdgcn_s_barrier();
}

// ---------------- tables + W->bf16 ----------------
__global__ void tables_k(const int* __restrict__ idx,
                         const float* __restrict__ wr, const float* __restrict__ wi,
                         unsigned short* __restrict__ T, unsigned short* __restrict__ IT,
                         unsigned short* __restrict__ WBr, unsigned short* __restrict__ WBi) {
  int gid = blockIdx.x * blockDim.x + threadIdx.x;  // 0..262143
  const float w0 = 6.283185307179586f / (float)NL;
  {
    int row = gid >> 11, l = gid & (NL - 1);
    int m = row & 63;
    int f = idx[m];
    float s, c;
    sincosf((float)((f * l) & (NL - 1)) * w0, &s, &c);
    T[gid] = f2bf(row < 64 ? c : -s);
  }
  {
    int lp = gid >> 7, k = gid & 127;
    int m = k & 63;
    float s, c;
    sincosf((float)((m * lp) & (NL - 1)) * w0, &s, &c);
    float v = (k < 64) ? ((m == 0 ? 1.0f : 2.0f) / (float)NL) * c
                       : (m == 0 ? 0.0f : (-2.0f / (float)NL) * s);
    IT[gid] = f2bf(v);
  }
  {
    const float2* wr2 = (const float2*)wr;
    const float2* wi2 = (const float2*)wi;
    unsigned int* obr = (unsigned int*)WBr;
    unsigned int* obi = (unsigned int*)WBi;
#pragma unroll
    for (int r = 0; r < 4; ++r) {
      int j = r * 262144 + gid;
      float2 a = wr2[j];
      float2 b2 = wi2[j];
      obr[j] = pk2(a.x, a.y);
      obi[j] = pk2(b2.x, b2.y);
    }
  }
}

// ---------------- fused per-(b,h) kernel ----------------
// 256 blocks x 512 thr. P1: X = T*q (MFMA K=2048), A direct-from-L2 (reg prefetch),
// q reg-ring->LDS, counted-wait barriers. P2: VALU complex mix (bf16 W from L2).
// P3: out = Ot * IT^T (MFMA, A from LDS regs, B direct from L2).
__global__ __launch_bounds__(512) void fused_k(const float* __restrict__ q,
                                               const unsigned short* __restrict__ T,
                                               const unsigned short* __restrict__ IT,
                                               const unsigned short* __restrict__ WBr,
                                               const unsigned short* __restrict__ WBi,
                                               float* __restrict__ out) {
  __shared__ __align__(16) char smem[53248];
  int t = threadIdx.x, lane = t & 63, wid = t >> 6;
  int h = blockIdx.x & 7, b = blockIdx.x >> 3;

  // ================= P1: DFT =================
  {
    char* b0 = smem + 34816;   // B buf 0: [e 64][l 64] bf16, 144B rows
    char* b1 = smem + 44032;   // B buf 1
    const float* qb = q + ((size_t)b * NL * NH + h) * NE;  // q[b][l][h][e]
    int mh = wid >> 1, eh = wid & 1;
    int eq = t >> 5, lp = t & 31;   // staging: 16 e-quads x 32 l-pairs
    f32x4 acc[2][2] = {};
    us8 aregA[4], aregB[4];
    f32x4 qregA[2], qregB[2];

    auto qload = [&](int c, f32x4* qr) {
#pragma unroll
      for (int j2 = 0; j2 < 2; ++j2)
        qr[j2] = *(const f32x4*)(qb + (size_t)(c * 64 + lp * 2 + j2) * (NH * NE) + eq * 4);
    };
    auto writesB = [&](const f32x4* qr, char* bb) {
#pragma unroll
      for (int j = 0; j < 4; ++j) {
        int e = eq * 4 + j;
        *(unsigned int*)(bb + e * 144 + lp * 4) = pk2(qr[0][j], qr[1][j]);
      }
    };
    auto loadA = [&](int c, us8* ar) {
#pragma unroll
      for (int ks2 = 0; ks2 < 2; ++ks2)
#pragma unroll
        for (int fm = 0; fm < 2; ++fm) {
          int row = mh * 32 + fm * 16 + (lane & 15);
          ar[ks2 * 2 + fm] = *(const us8*)(
              (const char*)T + (size_t)row * (NL * 2) +
              (size_t)(c * 64 + ks2 * 32 + (lane >> 4) * 8) * 2);
        }
    };
    auto compute = [&](const us8* ar, const char* bb) {
#pragma unroll
      for (int ks2 = 0; ks2 < 2; ++ks2) {
        bf16x8 bfr[2];
#pragma unroll
        for (int fn = 0; fn < 2; ++fn) {
          int e = eh * 32 + fn * 16 + (lane & 15);
          bfr[fn] = __builtin_bit_cast(
              bf16x8, *(const us8*)(bb + e * 144 + ks2 * 64 + (lane >> 4) * 16));
        }
#pragma unroll
        for (int fm = 0; fm < 2; ++fm) {
          bf16x8 afr = __builtin_bit_cast(bf16x8, ar[ks2 * 2 + fm]);
          acc[fm][0] = __builtin_amdgcn_mfma_f32_16x16x32_bf16(afr, bfr[0], acc[fm][0], 0, 0, 0);
          acc[fm][1] = __builtin_amdgcn_mfma_f32_16x16x32_bf16(afr, bfr[1], acc[fm][1], 0, 0, 0);
        }
      }
    };

    // prologue
    qload(0, qregA);
    qload(1, qregB);
    writesB(qregA, b0);     // auto-counted vmcnt wait on qregA only
    loadA(0, aregA);
    bar_lgkm();
    // main loop: manually 2x-unrolled so all reg indices are static (rule #20)
    for (int cc = 0; cc < 32; cc += 2) {
      // chunk cc (buffers *A, b0)
      loadA(cc + 1, aregB);
      compute(aregA, b0);
      __builtin_amdgcn_s_barrier();          // readers of b0 done
      writesB(qregB, b1);                    // chunk cc+1 -> b1
      if (cc + 2 < 32) qload(cc + 2, qregA);
      bar_lgkm();                            // b1 visible; loads stay in flight
      // chunk cc+1 (buffers *B, b1)
      if (cc + 2 < 32) loadA(cc + 2, aregA);
      compute(aregB, b1);
      __builtin_amdgcn_s_barrier();          // readers of b1 done
      if (cc + 2 < 32) {
        writesB(qregA, b0);                  // chunk cc+2 -> b0
        if (cc + 3 < 32) qload(cc + 3, qregB);
        bar_lgkm();
      }
    }
    // acc -> Xs fp32 [128 m_ri][272B rows], XOR ((row>>3)&7)<<4, at smem[0..34816)
#pragma unroll
    for (int fm = 0; fm < 2; ++fm)
#pragma unroll
      for (int fn = 0; fn < 2; ++fn)
#pragma unroll
        for (int r4 = 0; r4 < 4; ++r4) {
          int row = mh * 32 + fm * 16 + (lane >> 4) * 4 + r4;
          int col = eh * 32 + fn * 16 + (lane & 15);
          int off = (row * 272 + col * 4) ^ (((row >> 3) & 7) << 4);
          *(float*)(smem + off) = acc[fm][fn][r4];
        }
  }
  __syncthreads();

  // ================= P2: mix (fp32 VALU, bf16 W) =================
  {
    char* OtB = smem + 34816;           // [64 o][128 m_ri] bf16, 256B rows, XOR (o&7)<<4
    int o = t >> 3, mq = t & 7;         // thread: 1 o, 8 m (m = mq*8+mi)
    const unsigned short* wbr = WBr + (size_t)h * 262144 + (size_t)o * 64 + mq * 8;
    const unsigned short* wbi = WBi + (size_t)h * 262144 + (size_t)o * 64 + mq * 8;
    float orr[8] = {}, oii[8] = {};
    for (int ib = 0; ib < 16; ++ib) {
      f32x4 xr4[8], xi4[8];
#pragma unroll
      for (int mi = 0; mi < 8; ++mi) {
        int m = mq * 8 + mi;
        xr4[mi] = *(const f32x4*)(smem + ((m * 272 + ib * 16) ^ (mq << 4)));
        xi4[mi] = *(const f32x4*)(smem + (((64 + m) * 272 + ib * 16) ^ (mq << 4)));
      }
      us8 wr8[4], wi8[4];
#pragma unroll
      for (int ii = 0; ii < 4; ++ii) {
        int i = ib * 4 + ii;
        wr8[ii] = *(const us8*)(wbr + (size_t)i * 4096);
        wi8[ii] = *(const us8*)(wbi + (size_t)i * 4096);
      }
#pragma unroll
      for (int ii = 0; ii < 4; ++ii)
#pragma unroll
        for (int mi = 0; mi < 8; ++mi) {
          float wrv = bf2f(wr8[ii][mi]);
          float wiv = bf2f(wi8[ii][mi]);
          orr[mi] += xr4[mi][ii] * wrv - xi4[mi][ii] * wiv;
          oii[mi] += xr4[mi][ii] * wiv + xi4[mi][ii] * wrv;
        }
    }
    __syncthreads();   // P1's Xs fully consumed before OtB (overlaps nothing) -- order only
    uint4 vr = make_uint4(pk2(orr[0], orr[1]), pk2(orr[2], orr[3]),
                          pk2(orr[4], orr[5]), pk2(orr[6], orr[7]));
    uint4 vi = make_uint4(pk2(oii[0], oii[1]), pk2(oii[2], oii[3]),
                          pk2(oii[4], oii[5]), pk2(oii[6], oii[7]));
    *(uint4*)(OtB + ((o * 256 + mq * 16) ^ ((o & 7) << 4))) = vr;
    *(uint4*)(OtB + ((o * 256 + 128 + mq * 16) ^ ((o & 7) << 4))) = vi;
  }
  __syncthreads();

  // ================= P3: iDFT =================
  {
    const char* OtB = smem + 34816;
    bf16x8 af[2][8];
#pragma unroll
    for (int rg2 = 0; rg2 < 2; ++rg2)
#pragma unroll
      for (int ks = 0; ks < 8; ++ks) {
        int row = rg2 * 32 + (lane & 31);
        int off = (row * 256 + ks * 32 + (lane >> 5) * 16) ^ ((row & 7) << 4);
        af[rg2][ks] = __builtin_bit_cast(bf16x8, *(const us8*)(OtB + off));
      }
    float* ob = out + ((size_t)(b * 8 + h) * 64) * NL;
    int l0 = wid * 256;
    for (int ct = 0; ct < 8; ++ct) {
      int lr = l0 + ct * 32 + (lane & 31);
      f32x16 a2[2] = {};
#pragma unroll
      for (int ks = 0; ks < 8; ++ks) {
        bf16x8 bv = __builtin_bit_cast(
            bf16x8, *(const us8*)(IT + (size_t)lr * MRI + ks * 16 + (lane >> 5) * 8));
        a2[0] = __builtin_amdgcn_mfma_f32_32x32x16_bf16(af[0][ks], bv, a2[0], 0, 0, 0);
        a2[1] = __builtin_amdgcn_mfma_f32_32x32x16_bf16(af[1][ks], bv, a2[1], 0, 0, 0);
      }
#pragma unroll
      for (int rg2 = 0; rg2 < 2; ++rg2)
#pragma unroll
        for (int rg = 0; rg < 16; ++rg) {
          int row = rg2 * 32 + ((rg & 3) + 8 * (rg >> 2) + 4 * (lane >> 5));
          ob[(size_t)row * NL + lr] = a2[rg2][rg];
        }
    }
  }
}

extern "C" void kernel_launch(void* const* d_in, const int* in_sizes, int n_in,
                              void* d_out, int out_size, void* d_ws, size_t ws_size,
                              hipStream_t stream) {
  const float* q = (const float*)d_in[0];
  const float* wr = (const float*)d_in[3];
  const float* wi = (const float*)d_in[4];
  const int* idx = (const int*)d_in[5];
  float* out = (float*)d_out;
  char* ws = (char*)d_ws;

  constexpr size_t TBYTES = (size_t)MRI * NL * 2;            // 512 KB per table
  constexpr size_t WBBYTES = (size_t)NH * NE * NE * NM * 2;  // 4 MB per comp
  constexpr size_t NEED = 2 * TBYTES + 2 * WBBYTES;
  if (ws_size < NEED) return;

  unsigned short* T = (unsigned short*)ws;
  unsigned short* IT = (unsigned short*)(ws + TBYTES);
  unsigned short* WBr = (unsigned short*)(ws + 2 * TBYTES);
  unsigned short* WBi = (unsigned short*)(ws + 2 * TBYTES + WBBYTES);

  hipLaunchKernelGGL(tables_k, dim3(1024), dim3(256), 0, stream, idx, wr, wi, T, IT, WBr, WBi);
  hipLaunchKernelGGL(fused_k, dim3(NB * NH), dim3(512), 0, stream, q, T, IT, WBr, WBi, out);
}

// Round 9
// 87.168 us; speedup vs baseline: 1.2513x; 1.2513x over previous
//
#include <hip/hip_runtime.h>
#include <math.h>

#define NB 32
#define NL 2048
#define NH 8
#define NE 64
#define NM 64
#define MRI 128          // 2*NM (re stacked over im)
#define BK 128           // K per chunk
#define NCH 16           // 2048 / BK

typedef __attribute__((ext_vector_type(8))) __bf16 bf16x8;
typedef __attribute__((ext_vector_type(2))) __bf16 bf16x2;
typedef __attribute__((ext_vector_type(8))) unsigned short us8;
typedef __attribute__((ext_vector_type(4))) unsigned short us4;
typedef __attribute__((ext_vector_type(4))) float f32x4;
typedef __attribute__((ext_vector_type(16))) float f32x16;

__device__ __forceinline__ unsigned short f2bf(float x) {
  unsigned int u = __builtin_bit_cast(unsigned int, x);
  u = (u + 0x7fffu + ((u >> 16) & 1u)) >> 16;
  return (unsigned short)u;
}
__device__ __forceinline__ float bf2f(unsigned short u) {
  return __builtin_bit_cast(float, (unsigned int)u << 16);
}
__device__ __forceinline__ unsigned int pk2(float lo, float hi) {
  bf16x2 v;
  v[0] = (__bf16)lo;
  v[1] = (__bf16)hi;
  return __builtin_bit_cast(unsigned int, v);
}
__device__ __forceinline__ void gll16(const void* g, void* l) {
  __builtin_amdgcn_global_load_lds(
      (const __attribute__((address_space(1))) void*)g,
      (__attribute__((address_space(3))) void*)l, 16, 0, 0);
}
__device__ __forceinline__ void bar_lgkm() {
  asm volatile("s_waitcnt lgkmcnt(0)" ::: "memory");
  __builtin_amdgcn_s_barrier();
}

// ---------------- tables + W->bf16 ----------------
__global__ void tables_k(const int* __restrict__ idx,
                         const float* __restrict__ wr, const float* __restrict__ wi,
                         unsigned short* __restrict__ T, unsigned short* __restrict__ IT,
                         unsigned short* __restrict__ WBr, unsigned short* __restrict__ WBi) {
  int gid = blockIdx.x * blockDim.x + threadIdx.x;  // 0..262143
  const float w0 = 6.283185307179586f / (float)NL;
  {
    int row = gid >> 11, l = gid & (NL - 1);
    int m = row & 63;
    int f = idx[m];
    float s, c;
    sincosf((float)((f * l) & (NL - 1)) * w0, &s, &c);
    T[gid] = f2bf(row < 64 ? c : -s);
  }
  {
    int lp = gid >> 7, k = gid & 127;
    int m = k & 63;
    float s, c;
    sincosf((float)((m * lp) & (NL - 1)) * w0, &s, &c);
    float v = (k < 64) ? ((m == 0 ? 1.0f : 2.0f) / (float)NL) * c
                       : (m == 0 ? 0.0f : (-2.0f / (float)NL) * s);
    IT[gid] = f2bf(v);
  }
  {
    const float2* wr2 = (const float2*)wr;
    const float2* wi2 = (const float2*)wi;
    unsigned int* obr = (unsigned int*)WBr;
    unsigned int* obi = (unsigned int*)WBi;
#pragma unroll
    for (int r = 0; r < 4; ++r) {
      int j = r * 262144 + gid;
      float2 a = wr2[j];
      float2 b2 = wi2[j];
      obr[j] = pk2(a.x, a.y);
      obi[j] = pk2(b2.x, b2.y);
    }
  }
}

// ---------------- fused per-(b,h), 256 blocks x 1024 thr ----------------
// LDS map: Abuf dbuf 2x32768 @0 ; Bbuf dbuf 2x16896 @65536 (rows 264B)
//          Xs [128][272B] @0 (safe: last chunk reads Abuf1/Bbuf1) ; OtB @34816
__global__ __launch_bounds__(1024) void fused_k(const float* __restrict__ q,
                                                const unsigned short* __restrict__ T,
                                                const unsigned short* __restrict__ IT,
                                                const unsigned short* __restrict__ WBr,
                                                const unsigned short* __restrict__ WBi,
                                                float* __restrict__ out) {
  __shared__ __align__(16) char smem[99328];
  int t = threadIdx.x, lane = t & 63, wid = t >> 6;
  int h = blockIdx.x & 7, b = blockIdx.x >> 3;

  // ================= P1: DFT  X = T * q =================
  {
    char* Ab = smem;            // 2 x 32768, rows 256B, XOR (row&7)<<4
    char* B0 = smem + 65536;    // rows 264B
    char* B1 = smem + 65536 + 16896;
    const float* qb = q + ((size_t)b * NL * NH + h) * NE;  // q[b][l][h][e]
    int mh = wid >> 2, ehh = wid & 3;
    int eq = t & 15, lq = t >> 4;   // staging: e-quad (coalesced), l-pair
    f32x4 acc[2] = {};
    f32x4 qA[2], qB[2];

    auto qload = [&](int c, f32x4* qr) {
#pragma unroll
      for (int p = 0; p < 2; ++p)
        qr[p] = *(const f32x4*)(qb + (size_t)(c * BK + lq * 2 + p) * (NH * NE) + eq * 4);
    };
    auto writesB = [&](const f32x4* qr, char* bb) {
#pragma unroll
      for (int j = 0; j < 4; ++j) {
        int e = eq * 4 + j;
        *(unsigned int*)(bb + e * 264 + lq * 4) = pk2(qr[0][j], qr[1][j]);
      }
    };
    auto stageA = [&](int bufi, int c) {
#pragma unroll
      for (int n = 0; n < 2; ++n) {
        int lin = n * 16384 + t * 16;
        int row = lin >> 8;
        int colb = (lin & 255) ^ ((row & 7) << 4);
        gll16((const char*)T + (size_t)row * (NL * 2) + (size_t)c * 256 + colb,
              Ab + bufi * 32768 + lin);
      }
    };
    auto compute = [&](const char* ab, const char* bb) {
#pragma unroll
      for (int ks2 = 0; ks2 < 4; ++ks2) {
        int e = ehh * 16 + (lane & 15);
        int boff = e * 264 + ks2 * 64 + (lane >> 4) * 16;
        uint2 blo = *(const uint2*)(bb + boff);
        uint2 bhi = *(const uint2*)(bb + boff + 8);
        bf16x8 bfr = __builtin_bit_cast(bf16x8, make_uint4(blo.x, blo.y, bhi.x, bhi.y));
#pragma unroll
        for (int fm = 0; fm < 2; ++fm) {
          int row = mh * 32 + fm * 16 + (lane & 15);
          int aoff = (row * 256 + ks2 * 64 + (lane >> 4) * 16) ^ ((row & 7) << 4);
          bf16x8 afr = __builtin_bit_cast(bf16x8, *(const us8*)(ab + aoff));
          acc[fm] = __builtin_amdgcn_mfma_f32_16x16x32_bf16(afr, bfr, acc[fm], 0, 0, 0);
        }
      }
    };

    // prologue
    qload(0, qA);
    qload(1, qB);
    stageA(0, 0);
    writesB(qA, B0);
    asm volatile("s_waitcnt vmcnt(0)" ::: "memory");
    __builtin_amdgcn_sched_barrier(0);
    bar_lgkm();
    // main loop: 2 chunks per iter, counted vmcnt (q prefetch stays in flight)
    for (int c = 0; c < 14; c += 2) {
      stageA(1, c + 1);
      qload(c + 2, qA);
      compute(Ab, B0);
      asm volatile("s_waitcnt vmcnt(2)" ::: "memory");
      __builtin_amdgcn_sched_barrier(0);
      __builtin_amdgcn_s_barrier();
      writesB(qB, B1);
      bar_lgkm();

      stageA(0, c + 2);
      qload(c + 3, qB);
      compute(Ab + 32768, B1);
      asm volatile("s_waitcnt vmcnt(2)" ::: "memory");
      __builtin_amdgcn_sched_barrier(0);
      __builtin_amdgcn_s_barrier();
      writesB(qA, B0);
      bar_lgkm();
    }
    // c = 14
    stageA(1, 15);
    compute(Ab, B0);
    asm volatile("s_waitcnt vmcnt(0)" ::: "memory");
    __builtin_amdgcn_sched_barrier(0);
    __builtin_amdgcn_s_barrier();
    writesB(qB, B1);
    bar_lgkm();
    // c = 15
    compute(Ab + 32768, B1);
    __syncthreads();
    // acc -> Xs fp32 [128 m_ri][272B rows], XOR ((row>>3)&7)<<4
#pragma unroll
    for (int fm = 0; fm < 2; ++fm)
#pragma unroll
      for (int r4 = 0; r4 < 4; ++r4) {
        int row = mh * 32 + fm * 16 + (lane >> 4) * 4 + r4;
        int col = ehh * 16 + (lane & 15);
        int off = (row * 272 + col * 4) ^ (((row >> 3) & 7) << 4);
        *(float*)(smem + off) = acc[fm][r4];
      }
  }
  __syncthreads();

  // ================= P2: mix (fp32 VALU, bf16 W from L2) =================
  {
    char* OtB = smem + 34816;          // [64 o][128 m_ri] bf16, 256B rows, XOR (o&7)<<4
    int o = t >> 4, mq = t & 15;       // thread: 1 o, 4 m (m = mq*4+mi)
    const unsigned short* wbr = WBr + (size_t)h * 262144 + o * 64 + mq * 4;
    const unsigned short* wbi = WBi + (size_t)h * 262144 + o * 64 + mq * 4;
    float orr[4] = {}, oii[4] = {};
    for (int ib = 0; ib < 16; ++ib) {
      f32x4 xr4[4], xi4[4];
#pragma unroll
      for (int mi = 0; mi < 4; ++mi) {
        int m = mq * 4 + mi;
        xr4[mi] = *(const f32x4*)(smem + ((m * 272 + ib * 16) ^ (((m >> 3) & 7) << 4)));
        xi4[mi] = *(const f32x4*)(smem + (((64 + m) * 272 + ib * 16) ^ (((m >> 3) & 7) << 4)));
      }
      us4 wr4[4], wi4[4];
#pragma unroll
      for (int ii = 0; ii < 4; ++ii) {
        int i = ib * 4 + ii;
        wr4[ii] = *(const us4*)(wbr + (size_t)i * 4096);
        wi4[ii] = *(const us4*)(wbi + (size_t)i * 4096);
      }
#pragma unroll
      for (int ii = 0; ii < 4; ++ii)
#pragma unroll
        for (int mi = 0; mi < 4; ++mi) {
          float wrv = bf2f(wr4[ii][mi]);
          float wiv = bf2f(wi4[ii][mi]);
          orr[mi] += xr4[mi][ii] * wrv - xi4[mi][ii] * wiv;
          oii[mi] += xr4[mi][ii] * wiv + xi4[mi][ii] * wrv;
        }
    }
    uint2 vr = make_uint2(pk2(orr[0], orr[1]), pk2(orr[2], orr[3]));
    uint2 vi = make_uint2(pk2(oii[0], oii[1]), pk2(oii[2], oii[3]));
    *(uint2*)(OtB + ((o * 256 + mq * 8) ^ ((o & 7) << 4))) = vr;
    *(uint2*)(OtB + ((o * 256 + 128 + mq * 8) ^ ((o & 7) << 4))) = vi;
  }
  __syncthreads();

  // ================= P3: iDFT  out = Ot * IT^T =================
  {
    const char* OtB = smem + 34816;
    bf16x8 af[2][8];
#pragma unroll
    for (int rg2 = 0; rg2 < 2; ++rg2)
#pragma unroll
      for (int ks = 0; ks < 8; ++ks) {
        int row = rg2 * 32 + (lane & 31);
        int off = (row * 256 + ks * 32 + (lane >> 5) * 16) ^ ((row & 7) << 4);
        af[rg2][ks] = __builtin_bit_cast(bf16x8, *(const us8*)(OtB + off));
      }
    float* ob = out + ((size_t)(b * 8 + h) * 64) * NL;
    int l0 = wid * 128;
    for (int ct = 0; ct < 4; ++ct) {
      int lr = l0 + ct * 32 + (lane & 31);
      f32x16 a2[2] = {};
#pragma unroll
      for (int ks = 0; ks < 8; ++ks) {
        bf16x8 bv = __builtin_bit_cast(
            bf16x8, *(const us8*)(IT + (size_t)lr * MRI + ks * 16 + (lane >> 5) * 8));
        a2[0] = __builtin_amdgcn_mfma_f32_32x32x16_bf16(af[0][ks], bv, a2[0], 0, 0, 0);
        a2[1] = __builtin_amdgcn_mfma_f32_32x32x16_bf16(af[1][ks], bv, a2[1], 0, 0, 0);
      }
#pragma unroll
      for (int rg2 = 0; rg2 < 2; ++rg2)
#pragma unroll
        for (int rg = 0; rg < 16; ++rg) {
          int row = rg2 * 32 + ((rg & 3) + 8 * (rg >> 2) + 4 * (lane >> 5));
          ob[(size_t)row * NL + lr] = a2[rg2][rg];
        }
    }
  }
}

extern "C" void kernel_launch(void* const* d_in, const int* in_sizes, int n_in,
                              void* d_out, int out_size, void* d_ws, size_t ws_size,
                              hipStream_t stream) {
  const float* q = (const float*)d_in[0];
  const float* wr = (const float*)d_in[3];
  const float* wi = (const float*)d_in[4];
  const int* idx = (const int*)d_in[5];
  float* out = (float*)d_out;
  char* ws = (char*)d_ws;

  constexpr size_t TBYTES = (size_t)MRI * NL * 2;            // 512 KB per table
  constexpr size_t WBBYTES = (size_t)NH * NE * NE * NM * 2;  // 4 MB per comp
  constexpr size_t NEED = 2 * TBYTES + 2 * WBBYTES;
  if (ws_size < NEED) return;

  unsigned short* T = (unsigned short*)ws;
  unsigned short* IT = (unsigned short*)(ws + TBYTES);
  unsigned short* WBr = (unsigned short*)(ws + 2 * TBYTES);
  unsigned short* WBi = (unsigned short*)(ws + 2 * TBYTES + WBBYTES);

  hipLaunchKernelGGL(tables_k, dim3(1024), dim3(256), 0, stream, idx, wr, wi, T, IT, WBr, WBi);
  hipLaunchKernelGGL(fused_k, dim3(NB * NH), dim3(1024), 0, stream, q, T, IT, WBr, WBi, out);
}